// Round 21
// baseline (73.966 us; speedup 1.0000x reference)
//
#include <hip/hip_runtime.h>
#include <hip/hip_bf16.h>

typedef _Float16 f16x8 __attribute__((ext_vector_type(8)));
typedef _Float16 f16x4 __attribute__((ext_vector_type(4)));
typedef _Float16 f16x2 __attribute__((ext_vector_type(2)));
typedef __fp16   fp16v2 __attribute__((ext_vector_type(2)));   // cvt_pkrtz return type
typedef float    f32x4 __attribute__((ext_vector_type(4)));

#define E_TOT   6572
#define E4_TOT  1643
#define RSDW    36      // feature row stride dwords (144 B); 36%32=4
#define SETB    (64 * RSDW * 4)                   // 9216 B per wave's feature slice
#define H1RS    68      // h1T row stride dwords (272 B); 68%32=4; 32 rows = 8704 B

// d_ws layout (ushort indices):
// [0,8192) W0p | [8192,20480) W1p32 (x32 frags, r6 layout) |
// [20480,178208) em0h [6572][24] | [178208,257072) em1h [1643][48] |
// [257072,259120) W0X (x16 A-frags of W0 rows 0,1)
#define W1P_OFF  8192
#define EM0B_OFF 20480
#define EM1B_OFF 178208
#define W0X_OFF  257072
#define WS_TOT   259120

#if __has_builtin(__builtin_amdgcn_mfma_f32_16x16x16f16)
static __device__ __forceinline__ f32x4 MFMA16(f16x4 a, f16x4 b, f32x4 c) {
    return __builtin_amdgcn_mfma_f32_16x16x16f16(a, b, c, 0, 0, 0);
}
#else
static __device__ __forceinline__ f32x4 MFMA16(f16x4 a, f16x4 b, f32x4 c) {
    asm volatile("v_mfma_f32_16x16x16_f16 %0, %1, %2, %0"
                 : "+v"(c) : "v"(a), "v"(b));
    return c;
}
#endif

static __device__ __forceinline__ float clamp01(float v) {
    return __builtin_amdgcn_fmed3f(v, 0.0f, 1.0f);
}
static __device__ __forceinline__ unsigned cvt_pk_c01(float lo, float hi) {
    union { fp16v2 h; unsigned u; } r;
    r.h = __builtin_amdgcn_cvt_pkrtz(clamp01(lo), clamp01(hi));
    return r.u;
}
// packed-f16 lerp of one dword (2 elems): 2 VALU ops (v_pk_add + v_pk_fma)
static __device__ __forceinline__ unsigned lerp_h2(unsigned a, unsigned b, f16x2 p2) {
    union { unsigned u; f16x2 h; } A, B, R;
    A.u = a; B.u = b;
    R.h = A.h + p2 * (B.h - A.h);
    return R.u;
}
static __device__ __forceinline__ int bperm_i(int pt, int v) {
    return __builtin_amdgcn_ds_bpermute(pt << 2, v);
}
static __device__ __forceinline__ float bperm_f(int pt, float v) {
    union { float f; int i; } u, r;
    u.f = v;
    r.i = __builtin_amdgcn_ds_bpermute(pt << 2, u.i);
    return r.f;
}

// Feature k-order (as r14-r20):
//   k 0..43  = em1 col k      (W0 row 22+k)
//   k 44..63 = em0 col (k-44) (W0 row k-42)
// W0p: 16x16x32 f16 A-frag order, K=64 (as r19/r20).
// W1p32 (x32 A-frags, r6-verified layout): frag f = t1*4 + s1x (t1<6, s1x<4),
//   lane l, e<8 <- W1[k = 32*s1x + 8*(l>>4) + e][n = 16*t1 + (l&15)]
// W0X: x16 A-frags of W0 rows 0,1 (x-tail), as r20.
__global__ void pack_all(const float* __restrict__ W0, const float* __restrict__ W1,
                         const float* __restrict__ em0_w, const float* __restrict__ em1_w,
                         unsigned short* __restrict__ ws)
{
    int id = blockIdx.x * 256 + threadIdx.x;
    if (id >= WS_TOT) return;
    union { _Float16 h; unsigned short u; } cv;
    if (id < W1P_OFF) {                            // W0p: f = t*2+s, t<8, s<2
        int e = id & 7, l = (id >> 3) & 63, f = id >> 9;
        int g = l >> 4, c = l & 15;
        int s = f & 1, t = f >> 1;
        int k = s * 32 + g * 8 + e, n = t * 16 + c;
        int wrow = (k < 44) ? (22 + k) : (k - 42);  // em1-first permuted order
        cv.h = (_Float16)W0[wrow * 128 + n];
        ws[id] = cv.u;
    } else if (id < EM0B_OFF) {                    // W1p32: f = t1*4+s1x
        int id1 = id - W1P_OFF;
        int e = id1 & 7, l = (id1 >> 3) & 63, f = id1 >> 9;
        int g = l >> 4, c = l & 15;
        int s1x = f & 3, t1 = f >> 2;
        int k = 32 * s1x + 8 * g + e, n = 16 * t1 + c;
        cv.h = (_Float16)W1[k * 96 + n];
        ws[id] = cv.u;
    } else if (id < EM1B_OFF) {                    // em0h [6572][24]
        int qd = id - EM0B_OFF;
        int row = qd / 24, col = qd - row * 24;
        cv.h = (_Float16)(col < 20 ? em0_w[row * 20 + col] : 0.0f);
        ws[id] = cv.u;
    } else if (id < W0X_OFF) {                     // em1h [1643][48]
        int qd = id - EM1B_OFF;
        int row = qd / 48, col = qd - row * 48;
        cv.h = (_Float16)(col < 44 ? em1_w[row * 44 + col] : 0.0f);
        ws[id] = cv.u;
    } else {                                       // W0X x-tail frags
        int id1 = id - W0X_OFF;                    // [0,2048)
        int e2 = id1 & 3, l = (id1 >> 2) & 63, tt = id1 >> 8;
        int g = l >> 4, c = l & 15;
        int k = 4 * g + e2;
        cv.h = (_Float16)((k < 2) ? W0[k * 128 + 16 * tt + c] : 0.0f);
        ws[id] = cv.u;
    }
}

// r20 structure, but Layer 1 uses 16x16x32 MFMAs (96 instead of 192 x16):
// h1 crosses lanes via a per-half LDS round-trip reusing the (dead) feature
// slice -- the r6-verified write/read pattern. All wave-local, no barrier.
__global__ __launch_bounds__(256, 2) void fused_mlp(
    const float* __restrict__ x, const float* __restrict__ emb,
    const float* __restrict__ b0, const float* __restrict__ b1,
    const float* __restrict__ W2, const float* __restrict__ b2,
    const unsigned short* __restrict__ ws,
    float* __restrict__ out, int N)
{
    __shared__ __align__(16) char feat[4 * SETB];          // 36864 B feat/h1T
    __shared__ __align__(16) unsigned short wlds[20480];   // 40960 B: W0p|W1p32
    const unsigned short* em0h = ws + EM0B_OFF;
    const unsigned short* em1h = ws + EM1B_OFF;
    const unsigned short* w0x  = ws + W0X_OFF;             // 4 KB, L1-hot
    const unsigned short* w0s = wlds;
    const unsigned short* w1s = wlds + W1P_OFF;

    const int lane = threadIdx.x & 63;
    const int wid  = threadIdx.x >> 6;             // wave 0..3
    const int g    = lane >> 4, c = lane & 15;
    const int p    = blockIdx.x * 256 + wid * 64 + lane;
    const int pc   = min(p, N - 1);
    char* feat_lds = feat + wid * SETB;            // this wave's slice

    // ---- own-point loads FIRST (longest dependent chain starts earliest) ---
    const float t  = emb[pc];
    const float2 xv = *(const float2*)(x + 2 * pc);

    // ---- stage W0p+W1p32: exactly 2560 uint4 (40960 B), 10 per thread ------
    {
        const uint4* src = (const uint4*)ws;
        uint4* dst = (uint4*)wlds;
        #pragma unroll
        for (int i = 0; i < 10; ++i)
            dst[threadIdx.x + i * 256] = src[threadIdx.x + i * 256];
    }

    const int   i0 = (int)t;                       // i0 <= 6570 -> i0+1 valid
    const float pf = t - (float)i0;
    const float t4 = t * 0.25f;                    // exact
    const int   j0 = (int)t4;
    int   jb = j0;  float qf = t4 - (float)j0;
    if (j0 >= E4_TOT - 1) { jb = E4_TOT - 2; qf = 1.0f; }

    // ---- Phase A: COOPERATIVE gather+lerp -> this wave's feature rows -------
    // em1 (44 cols): 6 x 16B chunks/pt; slot G = it*64+lane -> pt=G/6, j=G%6
    #pragma unroll
    for (int it = 0; it < 6; ++it) {
        const int Gx = it * 64 + lane;
        const int pt = Gx / 6, j = Gx - pt * 6;
        const int   jbp = bperm_i(pt, jb);
        const float qfp = bperm_f(pt, qf);
        const unsigned short* src = em1h + jbp * 48 + j * 8;
        const uint4 r0 = *(const uint4*)(src);
        const uint4 r1 = *(const uint4*)(src + 48);
        const f16x2 q2 = {(_Float16)qfp, (_Float16)qfp};
        *(uint4*)(feat_lds + pt * (RSDW * 4) + j * 16) =
            make_uint4(lerp_h2(r0.x, r1.x, q2), lerp_h2(r0.y, r1.y, q2),
                       lerp_h2(r0.z, r1.z, q2), lerp_h2(r0.w, r1.w, q2));
    }
    // em0 (20 cols): 5 x 8B chunks/pt; overwrites em1's j=5 pad (bytes 88+)
    #pragma unroll
    for (int it = 0; it < 5; ++it) {
        const int Gx = it * 64 + lane;
        const int pt = Gx / 5, j = Gx - pt * 5;
        const int   i0p = bperm_i(pt, i0);
        const float pfp = bperm_f(pt, pf);
        const unsigned short* src = em0h + i0p * 24 + j * 4;
        const uint2 r0 = *(const uint2*)(src);
        const uint2 r1 = *(const uint2*)(src + 24);
        const f16x2 p2 = {(_Float16)pfp, (_Float16)pfp};
        *(uint2*)(feat_lds + pt * (RSDW * 4) + 88 + j * 8) =
            make_uint2(lerp_h2(r0.x, r1.x, p2), lerp_h2(r0.y, r1.y, p2));
    }

    __syncthreads();   // wlds visible to all waves (feat slices are wave-local)

    // ---- x of this lane's column-points -> f16-packed x16 B-frags ----------
    f16x4 bx[4];
    #pragma unroll
    for (int mt = 0; mt < 4; ++mt) {
        const float xa = bperm_f(16*mt + c, xv.x);
        const float xb = bperm_f(16*mt + c, xv.y);
        union { fp16v2 h; unsigned u; } cvx;
        cvx.h = __builtin_amdgcn_cvt_pkrtz(xa, xb);
        union { uint2 u2; f16x4 s; } B;
        B.u2 = make_uint2((g == 0) ? cvx.u : 0u, 0u);
        bx[mt] = B.s;
    }

    // ---- feature B-frags: lane (g,c) <- feat[k=32s+8g+e][pt=16mt+c] --------
    f16x8 a0f[4][2];
    #pragma unroll
    for (int mt = 0; mt < 4; ++mt)
        #pragma unroll
        for (int s = 0; s < 2; ++s)
            a0f[mt][s] = *(const f16x8*)(feat_lds + ((16*mt + c) * RSDW) * 4 + 64*s + 16*g);

    // ---- Layer 0: 2x 16x16x32 (K=64) + x16 x-tail per (tt,mt) --------------
    union U2S { uint2 u; f16x4 s; };
    f16x4 pb[8][4];
    #pragma unroll
    for (int tt = 0; tt < 8; ++tt) {
        f16x8 bw[2];
        #pragma unroll
        for (int s = 0; s < 2; ++s)
            bw[s] = *(const f16x8*)(w0s + ((tt*2 + s) << 9) + (lane << 3));
        const f16x4 ax = *(const f16x4*)(w0x + (tt << 8) + (lane << 2));
        const float4 b0v = *(const float4*)(b0 + tt*16 + g*4);  // b0[16t+4g+r]
        f32x4 acc[4];
        #pragma unroll
        for (int mt = 0; mt < 4; ++mt) acc[mt] = f32x4{b0v.x, b0v.y, b0v.z, b0v.w};
        #pragma unroll
        for (int s = 0; s < 2; ++s)
            #pragma unroll
            for (int mt = 0; mt < 4; ++mt)
                acc[mt] = __builtin_amdgcn_mfma_f32_16x16x32_f16(bw[s], a0f[mt][s], acc[mt], 0, 0, 0);
        #pragma unroll
        for (int mt = 0; mt < 4; ++mt)
            acc[mt] = MFMA16(ax, bx[mt], acc[mt]);  // x-tail (K=16, rows 0,1)
        #pragma unroll
        for (int mt = 0; mt < 4; ++mt) {
            U2S u2;
            u2.u = make_uint2(cvt_pk_c01(acc[mt][0], acc[mt][1]),
                              cvt_pk_c01(acc[mt][2], acc[mt][3]));
            pb[tt][mt] = u2.s;                     // h1[k=16t+4g+e][pt=16mt+c]
        }
    }

    // ---- Layer 1 (16x16x32, two pt-halves) + fused W2 ----------------------
    // Per half: write pb quads -> h1T[rows 16*m2+c][out] in the dead feature
    // slice (272B stride), read x32 B-frags (k-run 8g+e), 48 x32 MFMAs.
    // Wave-local LDS: in-order DS execution orders read/write hazards.
    float zp[4] = {0.f, 0.f, 0.f, 0.f};
    #pragma unroll
    for (int h = 0; h < 2; ++h) {
        #pragma unroll
        for (int tt = 0; tt < 8; ++tt)
            #pragma unroll
            for (int m2 = 0; m2 < 2; ++m2) {
                U2S u2; u2.s = pb[tt][2*h + m2];
                *(uint2*)(feat_lds + ((16*m2 + c) * H1RS + 8*tt + 2*g) * 4) = u2.u;
            }
        f16x8 hb[4][2];
        #pragma unroll
        for (int s1x = 0; s1x < 4; ++s1x)
            #pragma unroll
            for (int m2 = 0; m2 < 2; ++m2)
                hb[s1x][m2] = *(const f16x8*)(feat_lds + ((16*m2 + c) * H1RS + 16*s1x + 4*g) * 4);

        #pragma unroll
        for (int t1 = 0; t1 < 6; ++t1) {
            const float4 b1v = *(const float4*)(b1 + t1*16 + g*4);  // b1[16t1+4g+r]
            f32x4 acc2[2];
            #pragma unroll
            for (int m2 = 0; m2 < 2; ++m2) acc2[m2] = f32x4{b1v.x, b1v.y, b1v.z, b1v.w};
            #pragma unroll
            for (int s1x = 0; s1x < 4; ++s1x) {
                const f16x8 bw1 = *(const f16x8*)(w1s + ((t1*4 + s1x) << 9) + (lane << 3));
                #pragma unroll
                for (int m2 = 0; m2 < 2; ++m2)
                    acc2[m2] = __builtin_amdgcn_mfma_f32_16x16x32_f16(bw1, hb[s1x][m2], acc2[m2], 0, 0, 0);
            }
            const float4 w2v = *(const float4*)(W2 + t1*16 + g*4);  // W2[16t1+4g+r]
            #pragma unroll
            for (int m2 = 0; m2 < 2; ++m2) {
                zp[2*h + m2] = fmaf(clamp01(acc2[m2][0]), w2v.x, zp[2*h + m2]);
                zp[2*h + m2] = fmaf(clamp01(acc2[m2][1]), w2v.y, zp[2*h + m2]);
                zp[2*h + m2] = fmaf(clamp01(acc2[m2][2]), w2v.z, zp[2*h + m2]);
                zp[2*h + m2] = fmaf(clamp01(acc2[m2][3]), w2v.w, zp[2*h + m2]);
            }
        }
    }

    // ---- reduce over g-groups (4 lanes per pt-column), sigmoid, store ------
    float zr[4];
    #pragma unroll
    for (int mt = 0; mt < 4; ++mt) {
        float v = zp[mt];
        v += __shfl_xor(v, 16);
        v += __shfl_xor(v, 32);
        zr[mt] = v;                                // full z for pt=16mt+c
    }
    float z = (g == 0) ? zr[0] : (g == 1) ? zr[1] : (g == 2) ? zr[2] : zr[3];
    z += b2[0];
    z = 1.0f / (1.0f + __expf(-z));
    if (p < N) out[p] = z;                         // pt = 16g+c = lane: coalesced
}

extern "C" void kernel_launch(void* const* d_in, const int* in_sizes, int n_in,
                              void* d_out, int out_size, void* d_ws, size_t ws_size,
                              hipStream_t stream) {
    const float* x     = (const float*)d_in[0];
    const float* emb   = (const float*)d_in[1];
    const float* em0_w = (const float*)d_in[2];
    const float* em1_w = (const float*)d_in[3];
    const float* W0    = (const float*)d_in[4];
    const float* b0    = (const float*)d_in[5];
    const float* W1    = (const float*)d_in[6];
    const float* b1    = (const float*)d_in[7];
    const float* W2    = (const float*)d_in[8];
    const float* b2    = (const float*)d_in[9];
    float* out = (float*)d_out;
    const int N = in_sizes[1];

    unsigned short* ws = (unsigned short*)d_ws;    // 518240 B used

    pack_all<<<(WS_TOT + 255) / 256, 256, 0, stream>>>(W0, W1, em0_w, em1_w, ws);
    const int nb = (N + 255) / 256;
    fused_mlp<<<nb, 256, 0, stream>>>(x, emb, b0, b1, W2, b2, ws, out, N);
}

// Round 22
// 67.374 us; speedup vs baseline: 1.0978x; 1.0978x over previous
//
#include <hip/hip_runtime.h>
#include <hip/hip_bf16.h>

typedef _Float16 f16x8 __attribute__((ext_vector_type(8)));
typedef _Float16 f16x4 __attribute__((ext_vector_type(4)));
typedef _Float16 f16x2 __attribute__((ext_vector_type(2)));
typedef __fp16   fp16v2 __attribute__((ext_vector_type(2)));   // cvt_pkrtz return type
typedef float    f32x4 __attribute__((ext_vector_type(4)));

#define E_TOT   6572
#define E4_TOT  1643
#define RSDW    36      // LDS feature row stride dwords (144 B); 36%32=4
#define SETB    (64 * RSDW * 4)                   // 9216 B per wave's feature slice

// d_ws layout (ushort indices):
// [0,8192) W0p | [8192,20480) W1p16 paired | [20480,178208) em0h [6572][24] |
// [178208,257072) em1h [1643][48] | [257072,259120) W0X (x16 A-frags of W0 rows 0,1)
#define W1P_OFF  8192
#define EM0B_OFF 20480
#define EM1B_OFF 178208
#define W0X_OFF  257072
#define WS_TOT   259120

#if __has_builtin(__builtin_amdgcn_mfma_f32_16x16x16f16)
static __device__ __forceinline__ f32x4 MFMA16(f16x4 a, f16x4 b, f32x4 c) {
    return __builtin_amdgcn_mfma_f32_16x16x16f16(a, b, c, 0, 0, 0);
}
#else
static __device__ __forceinline__ f32x4 MFMA16(f16x4 a, f16x4 b, f32x4 c) {
    asm volatile("v_mfma_f32_16x16x16_f16 %0, %1, %2, %0"
                 : "+v"(c) : "v"(a), "v"(b));
    return c;
}
#endif

static __device__ __forceinline__ float clamp01(float v) {
    return __builtin_amdgcn_fmed3f(v, 0.0f, 1.0f);
}
static __device__ __forceinline__ unsigned cvt_pk_c01(float lo, float hi) {
    union { fp16v2 h; unsigned u; } r;
    r.h = __builtin_amdgcn_cvt_pkrtz(clamp01(lo), clamp01(hi));
    return r.u;
}
// packed-f16 lerp of one dword (2 elems): 2 VALU ops (v_pk_add + v_pk_fma)
static __device__ __forceinline__ unsigned lerp_h2(unsigned a, unsigned b, f16x2 p2) {
    union { unsigned u; f16x2 h; } A, B, R;
    A.u = a; B.u = b;
    R.h = A.h + p2 * (B.h - A.h);
    return R.u;
}
static __device__ __forceinline__ int bperm_i(int pt, int v) {
    return __builtin_amdgcn_ds_bpermute(pt << 2, v);
}
static __device__ __forceinline__ float bperm_f(int pt, float v) {
    union { float f; int i; } u, r;
    u.f = v;
    r.i = __builtin_amdgcn_ds_bpermute(pt << 2, u.i);
    return r.f;
}

// Feature k-order (as r14-r20):
//   k 0..43  = em1 col k      (W0 row 22+k)
//   k 44..63 = em0 col (k-44) (W0 row k-42)
// W0p: 16x16x32 f16 A-frag order, K=64.
// W1p16 (PAIRED x16 A-frags): pair p2 = q*6+t1, lane l, half h, e2<4
//   <- W1[k = 16*(2q+h)+4*(l>>4)+e2][n = 16t1+(l&15)]
// W0X: x16 A-frags of W0 rows 0,1 (x-tail): frag tt<8, lane l, e2<4
//   <- (k=4*(l>>4)+e2 < 2) ? W0[k][16tt+(l&15)] : 0.
__global__ void pack_all(const float* __restrict__ W0, const float* __restrict__ W1,
                         const float* __restrict__ em0_w, const float* __restrict__ em1_w,
                         unsigned short* __restrict__ ws)
{
    int id = blockIdx.x * 256 + threadIdx.x;
    if (id >= WS_TOT) return;
    union { _Float16 h; unsigned short u; } cv;
    if (id < W1P_OFF) {                            // W0p: f = t*2+s, t<8, s<2
        int e = id & 7, l = (id >> 3) & 63, f = id >> 9;
        int g = l >> 4, c = l & 15;
        int s = f & 1, t = f >> 1;
        int k = s * 32 + g * 8 + e, n = t * 16 + c;
        int wrow = (k < 44) ? (22 + k) : (k - 42);  // em1-first permuted order
        cv.h = (_Float16)W0[wrow * 128 + n];
        ws[id] = cv.u;
    } else if (id < EM0B_OFF) {                    // W1p16 paired
        int id1 = id - W1P_OFF;
        int e2 = id1 & 3, h = (id1 >> 2) & 1, l = (id1 >> 3) & 63, p2 = id1 >> 9;
        int g = l >> 4, c = l & 15;
        int q = p2 / 6, t1 = p2 - 6 * q;
        int s1 = 2 * q + h;
        int k = 16 * s1 + 4 * g + e2, n = 16 * t1 + c;
        cv.h = (_Float16)W1[k * 96 + n];
        ws[id] = cv.u;
    } else if (id < EM1B_OFF) {                    // em0h [6572][24]
        int qd = id - EM0B_OFF;
        int row = qd / 24, col = qd - row * 24;
        cv.h = (_Float16)(col < 20 ? em0_w[row * 20 + col] : 0.0f);
        ws[id] = cv.u;
    } else if (id < W0X_OFF) {                     // em1h [1643][48]
        int qd = id - EM1B_OFF;
        int row = qd / 48, col = qd - row * 48;
        cv.h = (_Float16)(col < 44 ? em1_w[row * 44 + col] : 0.0f);
        ws[id] = cv.u;
    } else {                                       // W0X x-tail frags
        int id1 = id - W0X_OFF;                    // [0,2048)
        int e2 = id1 & 3, l = (id1 >> 2) & 63, tt = id1 >> 8;
        int g = l >> 4, c = l & 15;
        int k = 4 * g + e2;
        cv.h = (_Float16)((k < 2) ? W0[k * 128 + 16 * tt + c] : 0.0f);
        ws[id] = cv.u;
    }
}

// r20 (best verified: 67.9 us) + emb/x loads hoisted above W-staging so their
// HBM latency overlaps the 40 KB LDS stage. L1 stays x16 (h1 in registers --
// r21 proved the x32 LDS round-trip costs more than the MFMA-shape saving).
__global__ __launch_bounds__(256, 2) void fused_mlp(
    const float* __restrict__ x, const float* __restrict__ emb,
    const float* __restrict__ b0, const float* __restrict__ b1,
    const float* __restrict__ W2, const float* __restrict__ b2,
    const unsigned short* __restrict__ ws,
    float* __restrict__ out, int N)
{
    __shared__ __align__(16) char feat[4 * SETB];          // 36864 B features
    __shared__ __align__(16) unsigned short wlds[20480];   // 40960 B: W0p|W1p
    const unsigned short* em0h = ws + EM0B_OFF;
    const unsigned short* em1h = ws + EM1B_OFF;
    const unsigned short* w0x  = ws + W0X_OFF;             // 4 KB, L1-hot
    const unsigned short* w0s = wlds;
    const unsigned short* w1s = wlds + W1P_OFF;

    const int lane = threadIdx.x & 63;
    const int wid  = threadIdx.x >> 6;             // wave 0..3
    const int g    = lane >> 4, c = lane & 15;
    const int p    = blockIdx.x * 256 + wid * 64 + lane;
    const int pc   = min(p, N - 1);
    char* feat_lds = feat + wid * SETB;            // this wave's feature slice

    // ---- own-point loads FIRST: longest dependent chain starts earliest ----
    const float t   = emb[pc];
    const float2 xv = *(const float2*)(x + 2 * pc);

    // ---- stage W0p+W1p: exactly 2560 uint4 (40960 B), 10 per thread --------
    {
        const uint4* src = (const uint4*)ws;
        uint4* dst = (uint4*)wlds;
        #pragma unroll
        for (int i = 0; i < 10; ++i)
            dst[threadIdx.x + i * 256] = src[threadIdx.x + i * 256];
    }

    const int   i0 = (int)t;                       // i0 <= 6570 -> i0+1 valid
    const float pf = t - (float)i0;
    const float t4 = t * 0.25f;                    // exact
    const int   j0 = (int)t4;
    int   jb = j0;  float qf = t4 - (float)j0;
    if (j0 >= E4_TOT - 1) { jb = E4_TOT - 2; qf = 1.0f; }

    // ---- Phase A: COOPERATIVE gather+lerp -> this wave's feature rows -------
    // em1 (44 cols): 6 x 16B chunks/pt; slot G = it*64+lane -> pt=G/6, j=G%6
    #pragma unroll
    for (int it = 0; it < 6; ++it) {
        const int Gx = it * 64 + lane;
        const int pt = Gx / 6, j = Gx - pt * 6;
        const int   jbp = bperm_i(pt, jb);
        const float qfp = bperm_f(pt, qf);
        const unsigned short* src = em1h + jbp * 48 + j * 8;
        const uint4 r0 = *(const uint4*)(src);
        const uint4 r1 = *(const uint4*)(src + 48);
        const f16x2 q2 = {(_Float16)qfp, (_Float16)qfp};
        *(uint4*)(feat_lds + pt * (RSDW * 4) + j * 16) =
            make_uint4(lerp_h2(r0.x, r1.x, q2), lerp_h2(r0.y, r1.y, q2),
                       lerp_h2(r0.z, r1.z, q2), lerp_h2(r0.w, r1.w, q2));
    }
    // em0 (20 cols): 5 x 8B chunks/pt; overwrites em1's j=5 pad (bytes 88+)
    #pragma unroll
    for (int it = 0; it < 5; ++it) {
        const int Gx = it * 64 + lane;
        const int pt = Gx / 5, j = Gx - pt * 5;
        const int   i0p = bperm_i(pt, i0);
        const float pfp = bperm_f(pt, pf);
        const unsigned short* src = em0h + i0p * 24 + j * 4;
        const uint2 r0 = *(const uint2*)(src);
        const uint2 r1 = *(const uint2*)(src + 24);
        const f16x2 p2 = {(_Float16)pfp, (_Float16)pfp};
        *(uint2*)(feat_lds + pt * (RSDW * 4) + 88 + j * 8) =
            make_uint2(lerp_h2(r0.x, r1.x, p2), lerp_h2(r0.y, r1.y, p2));
    }

    __syncthreads();   // wlds visible to all waves (features are wave-local)

    // ---- x of this lane's column-points -> f16-packed x16 B-frags ----------
    // bx[mt]: B[k][pt=16mt+c], k=0 -> x.x, k=1 -> x.y, else 0 (lanes g==0).
    f16x4 bx[4];
    #pragma unroll
    for (int mt = 0; mt < 4; ++mt) {
        const float xa = bperm_f(16*mt + c, xv.x);
        const float xb = bperm_f(16*mt + c, xv.y);
        union { fp16v2 h; unsigned u; } cvx;
        cvx.h = __builtin_amdgcn_cvt_pkrtz(xa, xb);
        union { uint2 u2; f16x4 s; } B;
        B.u2 = make_uint2((g == 0) ? cvx.u : 0u, 0u);
        bx[mt] = B.s;
    }

    // ---- feature B-frags: lane (g,c) <- feat[k=32s+8g+e][pt=16mt+c] --------
    f16x8 a0f[4][2];
    #pragma unroll
    for (int mt = 0; mt < 4; ++mt)
        #pragma unroll
        for (int s = 0; s < 2; ++s)
            a0f[mt][s] = *(const f16x8*)(feat_lds + ((16*mt + c) * RSDW) * 4 + 64*s + 16*g);

    // ---- Layer 0: 2x 16x16x32 (K=64) + 1x 16x16x16 x-tail per (tt,mt) ------
    union U2S { uint2 u; f16x4 s; };
    f16x4 pb[8][4];
    #pragma unroll
    for (int tt = 0; tt < 8; ++tt) {
        f16x8 bw[2];
        #pragma unroll
        for (int s = 0; s < 2; ++s)
            bw[s] = *(const f16x8*)(w0s + ((tt*2 + s) << 9) + (lane << 3));
        const f16x4 ax = *(const f16x4*)(w0x + (tt << 8) + (lane << 2));
        const float4 b0v = *(const float4*)(b0 + tt*16 + g*4);  // b0[16t+4g+r]
        f32x4 acc[4];
        #pragma unroll
        for (int mt = 0; mt < 4; ++mt) acc[mt] = f32x4{b0v.x, b0v.y, b0v.z, b0v.w};
        #pragma unroll
        for (int s = 0; s < 2; ++s)
            #pragma unroll
            for (int mt = 0; mt < 4; ++mt)
                acc[mt] = __builtin_amdgcn_mfma_f32_16x16x32_f16(bw[s], a0f[mt][s], acc[mt], 0, 0, 0);
        #pragma unroll
        for (int mt = 0; mt < 4; ++mt)
            acc[mt] = MFMA16(ax, bx[mt], acc[mt]);  // x-tail (K=16, rows 0,1)
        #pragma unroll
        for (int mt = 0; mt < 4; ++mt) {
            U2S u2;
            u2.u = make_uint2(cvt_pk_c01(acc[mt][0], acc[mt][1]),
                              cvt_pk_c01(acc[mt][2], acc[mt][3]));
            pb[tt][mt] = u2.s;                     // h1[k=16t+4g+e][pt=16mt+c]
        }
    }

    // ---- Layer 1 (16x16x16 f16, swapped) + fused W2; W1 frags from LDS -----
    float zp[4] = {0.f, 0.f, 0.f, 0.f};
    #pragma unroll
    for (int t1 = 0; t1 < 6; ++t1) {
        const float4 b1v = *(const float4*)(b1 + t1*16 + g*4);  // b1[16t1+4g+r]
        f32x4 acc[4];
        #pragma unroll
        for (int mt = 0; mt < 4; ++mt) acc[mt] = f32x4{b1v.x, b1v.y, b1v.z, b1v.w};
        #pragma unroll
        for (int q = 0; q < 4; ++q) {              // one LDS b128 = frags s1=2q,2q+1
            const f16x8 pr = *(const f16x8*)(w1s + ((q*6 + t1) << 9) + (lane << 3));
            f16x4 lo, hi;
            lo[0]=pr[0]; lo[1]=pr[1]; lo[2]=pr[2]; lo[3]=pr[3];
            hi[0]=pr[4]; hi[1]=pr[5]; hi[2]=pr[6]; hi[3]=pr[7];
            #pragma unroll
            for (int mt = 0; mt < 4; ++mt)
                acc[mt] = MFMA16(lo, pb[2*q][mt], acc[mt]);
            #pragma unroll
            for (int mt = 0; mt < 4; ++mt)
                acc[mt] = MFMA16(hi, pb[2*q + 1][mt], acc[mt]);
        }
        const float4 w2v = *(const float4*)(W2 + t1*16 + g*4);  // W2[16t1+4g+r]
        #pragma unroll
        for (int mt = 0; mt < 4; ++mt) {
            zp[mt] = fmaf(clamp01(acc[mt][0]), w2v.x, zp[mt]);
            zp[mt] = fmaf(clamp01(acc[mt][1]), w2v.y, zp[mt]);
            zp[mt] = fmaf(clamp01(acc[mt][2]), w2v.z, zp[mt]);
            zp[mt] = fmaf(clamp01(acc[mt][3]), w2v.w, zp[mt]);
        }
    }

    // ---- reduce over g-groups (4 lanes per pt-column), sigmoid, store ------
    float zr[4];
    #pragma unroll
    for (int mt = 0; mt < 4; ++mt) {
        float v = zp[mt];
        v += __shfl_xor(v, 16);
        v += __shfl_xor(v, 32);
        zr[mt] = v;                                // full z for pt=16mt+c
    }
    float z = (g == 0) ? zr[0] : (g == 1) ? zr[1] : (g == 2) ? zr[2] : zr[3];
    z += b2[0];
    z = 1.0f / (1.0f + __expf(-z));
    if (p < N) out[p] = z;                         // pt = 16g+c = lane: coalesced
}

extern "C" void kernel_launch(void* const* d_in, const int* in_sizes, int n_in,
                              void* d_out, int out_size, void* d_ws, size_t ws_size,
                              hipStream_t stream) {
    const float* x     = (const float*)d_in[0];
    const float* emb   = (const float*)d_in[1];
    const float* em0_w = (const float*)d_in[2];
    const float* em1_w = (const float*)d_in[3];
    const float* W0    = (const float*)d_in[4];
    const float* b0    = (const float*)d_in[5];
    const float* W1    = (const float*)d_in[6];
    const float* b1    = (const float*)d_in[7];
    const float* W2    = (const float*)d_in[8];
    const float* b2    = (const float*)d_in[9];
    float* out = (float*)d_out;
    const int N = in_sizes[1];

    unsigned short* ws = (unsigned short*)d_ws;    // 518240 B used

    pack_all<<<(WS_TOT + 255) / 256, 256, 0, stream>>>(W0, W1, em0_w, em1_w, ws);
    const int nb = (N + 255) / 256;
    fused_mlp<<<nb, 256, 0, stream>>>(x, emb, b0, b1, W2, b2, ws, out, N);
}